// Round 7
// baseline (320.424 us; speedup 1.0000x reference)
//
#include <hip/hip_runtime.h>
#include <hip/hip_bf16.h>
#include <stdint.h>

// DynamicSparseAttention MI355X r15 — fp32 I/O.
// History: r9 @322 (attn 148). r10 spill fail. r11-r13: block-config changes
// all slower (occupancy pinned ~40% regardless of LDS/VGPR; dur = per-block
// critical path). r14 @317 (attn 142.8): wave-independent tail, 3->1 barriers
// (-5us; barriers were minor). Busy cycles invariant -> remaining stall is
// intra-wave serial latency. r15 attacks both serial chains with ILP:
// (1) score: accC split into accC0/accC1 -> 4 indep MFMA chains depth<=6
//     (was 10-deep dependent chain);
// (2) selection: the wave's two queries fully INTERLEAVED (bins q0 in row
//     2wv, bins q1 in row 2wv+1, selW/selI at row 2wv+1 + 512) -> fences
//     12->6, every dependent chain (scan/rank/softmax) gets 2-way ILP.
// gemm_qk / gemm_nl2 / presplit unchanged.

typedef __bf16 bf16_t;
typedef bf16_t bf16x8 __attribute__((ext_vector_type(8)));
typedef bf16_t bf16x4 __attribute__((ext_vector_type(4)));
typedef float  f32x4  __attribute__((ext_vector_type(4)));

#define NB 2
#define SS 1024
#define EE 1024
#define NH 16
#define HD 64
#define NBH (NB*NH)
#define NX_ ((size_t)NB*SS*EE)   // 2,097,152
#define NW_ ((size_t)EE*EE)      // 1,048,576

__device__ __forceinline__ f32x4 mfma16(bf16x8 a, bf16x8 b, f32x4 c) {
  return __builtin_amdgcn_mfma_f32_16x16x32_bf16(a, b, c, 0, 0, 0);
}

__device__ __forceinline__ void split3(float x, bf16_t& h, bf16_t& m, bf16_t& l) {
  h = (bf16_t)x;
  float r = x - (float)h;     // exact
  m = (bf16_t)r;
  float r2 = r - (float)m;    // exact
  l = (bf16_t)r2;             // residual <= 2^-27 |x|
}

// wave-local LDS ordering fence (per-wave scratch; no cross-wave deps)
__device__ __forceinline__ void wave_fence() {
  __builtin_amdgcn_wave_barrier();
  __builtin_amdgcn_s_waitcnt(0);
  __builtin_amdgcn_wave_barrier();
}

// async global->LDS, 16B per lane; LDS dest = wave-uniform base + lane*16
__device__ __forceinline__ void gld16(const bf16_t* g, bf16_t* l) {
  __builtin_amdgcn_global_load_lds(
      (const __attribute__((address_space(1))) void*)g,
      (__attribute__((address_space(3))) void*)l, 16, 0, 0);
}

// ---------------------------------------------------------------------------
// fused presplit of x, Wq, Wk, Wv, Wo into h/m/l limb arrays (unchanged)
// ---------------------------------------------------------------------------
__global__ __launch_bounds__(256) void presplit_all(
    const float* __restrict__ x,  const float* __restrict__ wq,
    const float* __restrict__ wk, const float* __restrict__ wv,
    const float* __restrict__ wo, bf16_t* __restrict__ base)
{
  const int blk = blockIdx.x;
  const float* src; bf16_t* h; size_t n; int i;
  if (blk < 2048)      { src = x;  h = base;                   n = NX_; i = blk;        }
  else if (blk < 3072) { src = wq; h = base + 3*NX_;           n = NW_; i = blk - 2048; }
  else if (blk < 4096) { src = wk; h = base + 3*NX_ + 3*NW_;   n = NW_; i = blk - 3072; }
  else if (blk < 5120) { src = wv; h = base + 3*NX_ + 6*NW_;   n = NW_; i = blk - 4096; }
  else                 { src = wo; h = base + 3*NX_ + 9*NW_;   n = NW_; i = blk - 5120; }
  bf16_t* m = h + n;
  bf16_t* l = m + n;
  int idx = i * 256 + threadIdx.x;            // float4 index
  float4 v = ((const float4*)src)[idx];
  float t[4] = { v.x, v.y, v.z, v.w };
  bf16x4 hv, mv, lv;
#pragma unroll
  for (int j = 0; j < 4; j++) {
    bf16_t a, b, c;
    split3(t[j], a, b, c);
    hv[j] = a; mv[j] = b; lv[j] = c;
  }
  ((bf16x4*)h)[idx] = hv;
  ((bf16x4*)m)[idx] = mv;
  ((bf16x4*)l)[idx] = lv;
}

// ---------------------------------------------------------------------------
// Fused Q+K projection GEMM, 128x64 tile. grid (16, 16, 2) = 512 blocks
// (exactly 2/CU co-resident). blockIdx.z selects Wq->q or Wk->k.
// (unchanged from r9)
// ---------------------------------------------------------------------------
__global__ __launch_bounds__(256, 2) void gemm_qk(
    const bf16_t* __restrict__ Ah, const bf16_t* __restrict__ Am,
    const bf16_t* __restrict__ Al,
    const bf16_t* __restrict__ Bqh, const bf16_t* __restrict__ Bqm,
    const bf16_t* __restrict__ Bql,
    const bf16_t* __restrict__ Bkh, const bf16_t* __restrict__ Bkm,
    const bf16_t* __restrict__ Bkl,
    const float* __restrict__ biasq, const float* __restrict__ biask,
    bf16_t* __restrict__ qH, bf16_t* __restrict__ qM, bf16_t* __restrict__ qL,
    bf16_t* __restrict__ kH, bf16_t* __restrict__ kM, bf16_t* __restrict__ kL)
{
  __shared__ bf16_t As[3][128 * 32];   // row-major, unpadded (gld16 lane order)
  __shared__ bf16_t Bs[3][64 * 32];

  const int z = blockIdx.z;
  const bf16_t* AP[3] = { Ah, Am, Al };
  const bf16_t* BP[3] = { z ? Bkh : Bqh, z ? Bkm : Bqm, z ? Bkl : Bql };
  const float* bias = z ? biask : biasq;
  bf16_t* dH = z ? kH : qH;
  bf16_t* dM = z ? kM : qM;
  bf16_t* dL = z ? kL : qL;

  const int tid  = threadIdx.x;
  const int wv   = tid >> 6, lane = tid & 63;
  const int quad = lane >> 4, l16 = lane & 15;
  const int m0 = blockIdx.y * 128, n0 = blockIdx.x * 64;
  const int wm = (wv & 1) * 64, wn = (wv >> 1) * 32;

  // staging: A rows [wv*32, wv*32+32) via two gld16; B rows [wv*16, wv*16+16)
  const int arow = wv * 32 + (lane >> 2);
  const int brow = wv * 16 + (lane >> 2);
  const int q8   = (lane & 3) * 8;
  const size_t aoff0 = (size_t)(m0 + arow) * 1024 + q8;
  const size_t boff  = (size_t)(n0 + brow) * 1024 + q8;

  f32x4 accH0[4][2] = {};   // hh, k < 512
  f32x4 accH1[4][2] = {};   // hh, k >= 512
  f32x4 accC [4][2] = {};   // corrections (small magnitude)

  for (int k0 = 0; k0 < 1024; k0 += 32) {
    __syncthreads();                     // previous iter's frags consumed
#pragma unroll
    for (int L = 0; L < 3; L++) {
      gld16(AP[L] + aoff0 + k0,              &As[L][(wv * 32) * 32]);
      gld16(AP[L] + aoff0 + 16 * 1024 + k0,  &As[L][(wv * 32 + 16) * 32]);
      gld16(BP[L] + boff + k0,               &Bs[L][(wv * 16) * 32]);
    }
    __syncthreads();                     // staging visible

    bf16x8 bfr[2][3];
#pragma unroll
    for (int nt = 0; nt < 2; nt++)
#pragma unroll
      for (int L = 0; L < 3; L++)
        bfr[nt][L] = *(const bf16x8*)&Bs[L][(wn + nt * 16 + l16) * 32 + quad * 8];

    const bool hi = (k0 >= 512);
#pragma unroll
    for (int mt = 0; mt < 4; mt++) {
      bf16x8 af[3];
#pragma unroll
      for (int L = 0; L < 3; L++)
        af[L] = *(const bf16x8*)&As[L][(wm + mt * 16 + l16) * 32 + quad * 8];
#pragma unroll
      for (int nt = 0; nt < 2; nt++) {
        f32x4& H = hi ? accH1[mt][nt] : accH0[mt][nt];
        H = mfma16(af[0], bfr[nt][0], H);                      // hh
        f32x4 c = accC[mt][nt];
        c = mfma16(af[0], bfr[nt][1], c);                      // hm
        c = mfma16(af[1], bfr[nt][0], c);                      // mh
        c = mfma16(af[0], bfr[nt][2], c);                      // hl
        c = mfma16(af[2], bfr[nt][0], c);                      // lh
        c = mfma16(af[1], bfr[nt][1], c);                      // mm
        accC[mt][nt] = c;
      }
    }
  }

  // epilogue: D[row=quad*4+r][col=l16] -> 3-way split limbs at [B,H,S,HD]
#pragma unroll
  for (int mt = 0; mt < 4; mt++)
#pragma unroll
  for (int nt = 0; nt < 2; nt++)
#pragma unroll
  for (int r  = 0; r  < 4;  r++) {
    int gm = m0 + wm + mt * 16 + quad * 4 + r;
    int gn = n0 + wn + nt * 16 + l16;
    float v = (accH0[mt][nt][r] + accH1[mt][nt][r]) + accC[mt][nt][r] + bias[gn];
    int b_ = gm >> 10, s_ = gm & 1023, h_ = gn >> 6, d_ = gn & 63;
    size_t di = (((size_t)b_ * NH + h_) * SS + s_) * HD + d_;
    bf16_t hh, mm, ll;
    split3(v, hh, mm, ll);
    dH[di] = hh; dM[di] = mm; dL[di] = ll;
  }
}

// ---------------------------------------------------------------------------
// 3-product NT GEMM (hh k-split + hm/mh corrections), 64x64 tile, grid (16,32).
// MODE 1: fp32 [B,H,S,HD] (v-proj).  MODE 2: fp32 row-major [M,N] (o-proj).
// (unchanged from r8)
// ---------------------------------------------------------------------------
template<int MODE>
__global__ __launch_bounds__(256, 4) void gemm_nl2(
    const bf16_t* __restrict__ Ah, const bf16_t* __restrict__ Am,
    const bf16_t* __restrict__ Bh, const bf16_t* __restrict__ Bm,
    const float* __restrict__ bias, float* __restrict__ dF)
{
  __shared__ bf16_t As[2][64 * 32];
  __shared__ bf16_t Bs[2][64 * 32];

  const bf16_t* AP[2] = { Ah, Am };
  const bf16_t* BP[2] = { Bh, Bm };

  const int tid  = threadIdx.x;
  const int wv   = tid >> 6, lane = tid & 63;
  const int quad = lane >> 4, l16 = lane & 15;
  const int m0 = blockIdx.y * 64, n0 = blockIdx.x * 64;
  const int wm = (wv & 1) * 32, wn = (wv >> 1) * 32;

  const int srow = wv * 16 + (lane >> 2);
  const int q8   = (lane & 3) * 8;
  const size_t aoff = (size_t)(m0 + srow) * 1024 + q8;
  const size_t boff = (size_t)(n0 + srow) * 1024 + q8;

  f32x4 accH0[2][2] = {};
  f32x4 accH1[2][2] = {};
  f32x4 accC [2][2] = {};

  for (int k0 = 0; k0 < 1024; k0 += 32) {
    __syncthreads();
#pragma unroll
    for (int L = 0; L < 2; L++) {
      gld16(AP[L] + aoff + k0, &As[L][(wv * 16) * 32]);
      gld16(BP[L] + boff + k0, &Bs[L][(wv * 16) * 32]);
    }
    __syncthreads();

    bf16x8 bfr[2][2];
#pragma unroll
    for (int nt = 0; nt < 2; nt++)
#pragma unroll
      for (int L = 0; L < 2; L++)
        bfr[nt][L] = *(const bf16x8*)&Bs[L][(wn + nt * 16 + l16) * 32 + quad * 8];

    const bool hi = (k0 >= 512);
#pragma unroll
    for (int mt = 0; mt < 2; mt++) {
      bf16x8 af[2];
#pragma unroll
      for (int L = 0; L < 2; L++)
        af[L] = *(const bf16x8*)&As[L][(wm + mt * 16 + l16) * 32 + quad * 8];
#pragma unroll
      for (int nt = 0; nt < 2; nt++) {
        f32x4& H = hi ? accH1[mt][nt] : accH0[mt][nt];
        H = mfma16(af[0], bfr[nt][0], H);                      // hh
        f32x4 c = accC[mt][nt];
        c = mfma16(af[0], bfr[nt][1], c);                      // hm
        c = mfma16(af[1], bfr[nt][0], c);                      // mh
        accC[mt][nt] = c;
      }
    }
  }

#pragma unroll
  for (int mt = 0; mt < 2; mt++)
#pragma unroll
  for (int nt = 0; nt < 2; nt++)
#pragma unroll
  for (int r  = 0; r  < 4;  r++) {
    int gm = m0 + wm + mt * 16 + quad * 4 + r;
    int gn = n0 + wn + nt * 16 + l16;
    float v = (accH0[mt][nt][r] + accH1[mt][nt][r]) + accC[mt][nt][r] + bias[gn];
    if (MODE == 2) {
      dF[(size_t)gm * 1024 + gn] = v;
    } else {
      int b_ = gm >> 10, s_ = gm & 1023, h_ = gn >> 6, d_ = gn & 63;
      dF[(((size_t)b_ * NH + h_) * SS + s_) * HD + d_] = v;
    }
  }
}

// ---------------------------------------------------------------------------
// Fused attention r15: one (b,h) x 16 queries, 512 thr / 8 waves.
// Score phase: single-chunk 16x1028 transpose, wave wv covers keys
// [wv*128,+128); accC split into 2 chains (4 indep MFMA chains, depth<=6).
// ONE block barrier. Tail wave-independent (r14) with the two owned queries
// fully interleaved: bins q0 = sc row 2wv, bins q1 = sc row 2wv+1,
// selW/selI at row 2wv+1 + 512 floats. 6 wave fences total.
// PV: wave-local, 16-deep batched gather, shfl_xor(16) reduce.
// ---------------------------------------------------------------------------
__global__ __launch_bounds__(512, 4) void attn_topk(
    const bf16_t* __restrict__ qhg, const bf16_t* __restrict__ qmg,
    const bf16_t* __restrict__ qlg,
    const bf16_t* __restrict__ khg, const bf16_t* __restrict__ kmg,
    const bf16_t* __restrict__ klg,
    const float*  __restrict__ vg,
    bf16_t* __restrict__ attnH, bf16_t* __restrict__ attnM)
{
  __shared__ float sc[16 * 1028];       // scores; rows become per-wave scratch

  const int tid  = threadIdx.x;
  const int wv   = tid >> 6, lane = tid & 63;
  const int quad = lane >> 4, l16 = lane & 15;
  const int xcd = blockIdx.x & 7;
  const int g   = blockIdx.x >> 3;        // 0..255
  const int bh  = xcd + 8 * (g >> 6);     // 0..31 (bh pinned to XCD)
  const int qt  = g & 63;
  const int b_ = bh >> 4, h_ = bh & 15;
  const int q0 = qt * 16;

  // A-frags direct from global: lane holds q[m=l16][k=quad*8+j]
  const size_t qbase = ((size_t)bh * SS + q0 + l16) * HD + quad * 8;
  bf16x8 aH[2], aM[2], aL[2];
#pragma unroll
  for (int ks = 0; ks < 2; ks++) {
    aH[ks] = *(const bf16x8*)(qhg + qbase + ks * 32);
    aM[ks] = *(const bf16x8*)(qmg + qbase + ks * 32);
    aL[ks] = *(const bf16x8*)(qlg + qbase + ks * 32);
  }

  // ---- score phase: wave wv covers keys [wv*128, wv*128+128) ----
  // 4 independent MFMA chains: accA (hh half0), accB (hh half1),
  // accC0 (corrections half0), accC1 (corrections half1).
  const size_t kwb = ((size_t)bh * SS + wv * 128 + l16) * HD + quad * 8;
#pragma unroll 4
  for (int t2 = 0; t2 < 8; t2++) {
    const size_t kb = kwb + (size_t)t2 * 16 * HD;
    bf16x8 bH0 = *(const bf16x8*)(khg + kb);
    bf16x8 bH1 = *(const bf16x8*)(khg + kb + 32);
    bf16x8 bM0 = *(const bf16x8*)(kmg + kb);
    bf16x8 bM1 = *(const bf16x8*)(kmg + kb + 32);
    bf16x8 bL0 = *(const bf16x8*)(klg + kb);
    bf16x8 bL1 = *(const bf16x8*)(klg + kb + 32);
    f32x4 accA = {}, accB = {}, accC0 = {}, accC1 = {};
    accA  = mfma16(aH[0], bH0, accA );           // hh, k-half 0
    accB  = mfma16(aH[1], bH1, accB );           // hh, k-half 1
    accC0 = mfma16(aH[0], bM0, accC0);           // hm half0
    accC1 = mfma16(aH[1], bM1, accC1);           // hm half1
    accC0 = mfma16(aM[0], bH0, accC0);           // mh half0
    accC1 = mfma16(aM[1], bH1, accC1);           // mh half1
    accC0 = mfma16(aH[0], bL0, accC0);           // hl half0
    accC1 = mfma16(aH[1], bL1, accC1);           // hl half1
    accC0 = mfma16(aL[0], bH0, accC0);           // lh half0
    accC1 = mfma16(aL[1], bH1, accC1);           // lh half1
    accC0 = mfma16(aM[0], bM0, accC0);           // mm half0
    accC1 = mfma16(aM[1], bM1, accC1);           // mm half1
    int key = wv * 128 + t2 * 16 + l16;
#pragma unroll
    for (int r = 0; r < 4; r++)
      sc[(quad * 4 + r) * 1028 + key] =
          ((accA[r] + accB[r]) + (accC0[r] + accC1[r])) * 0.125f;
  }
  __syncthreads();                        // the ONLY block barrier

  // ---- wave wv owns queries 2wv, 2wv+1 (sc rows 2wv, 2wv+1) ----
  float fv[2][16];
#pragma unroll
  for (int i = 0; i < 16; i++) {
    fv[0][i] = sc[(2 * wv)     * 1028 + i * 64 + lane];
    fv[1][i] = sc[(2 * wv + 1) * 1028 + i * 64 + lane];
  }
  wave_fence();                           // row reads done before overlay

  // wave-owned scratch inside the wave's own rows:
  // row 2wv   : bins0 (512 u32) -> candV0/candI0 after scan
  // row 2wv+1 : bins1 (512 u32) -> candV1/candI1 ; selW (128f) @+512 ;
  //             selI (128 u16) @+640
  uint32_t* bins0 = (uint32_t*)(sc + (2 * wv)     * 1028);
  uint32_t* bins1 = (uint32_t*)(sc + (2 * wv + 1) * 1028);
  float*    candV0 = (float*)bins0;
  ushort*   candI0 = (ushort*)(bins0 + 64);
  float*    candV1 = (float*)bins1;
  ushort*   candI1 = (ushort*)(bins1 + 64);
  float*    selWw = sc + (2 * wv + 1) * 1028 + 512;      // 128 floats
  ushort*   selIw = (ushort*)(selWw + 128);              // 128 u16

  const uint64_t lt = (1ull << lane) - 1ull;
  {
    // zero both bin arrays
    *(uint4*)(bins0 + lane * 8)     = uint4{0, 0, 0, 0};
    *(uint4*)(bins0 + lane * 8 + 4) = uint4{0, 0, 0, 0};
    *(uint4*)(bins1 + lane * 8)     = uint4{0, 0, 0, 0};
    *(uint4*)(bins1 + lane * 8 + 4) = uint4{0, 0, 0, 0};
    wave_fence();                                          // F1
    // interleaved histograms: bin = clamp((int)(f*32+256),0,511)
#pragma unroll
    for (int i = 0; i < 16; i++) {
      int b0 = (int)fmaxf(0.f, fminf(511.f, fmaf(fv[0][i], 32.f, 256.f)));
      int b1 = (int)fmaxf(0.f, fminf(511.f, fmaf(fv[1][i], 32.f, 256.f)));
      atomicAdd(bins0 + b0, 1u);
      atomicAdd(bins1 + b1, 1u);
    }
    wave_fence();                                          // F2
    // interleaved descending scans: lane covers bins [504-8*lane, 511-8*lane]
    int base = 504 - 8 * lane;
    uint4 ha0 = *(const uint4*)(bins0 + base);
    uint4 hb0 = *(const uint4*)(bins0 + base + 4);
    uint4 ha1 = *(const uint4*)(bins1 + base);
    uint4 hb1 = *(const uint4*)(bins1 + base + 4);
    uint32_t sl0 = ha0.x + ha0.y + ha0.z + ha0.w + hb0.x + hb0.y + hb0.z + hb0.w;
    uint32_t sl1 = ha1.x + ha1.y + ha1.z + ha1.w + hb1.x + hb1.y + hb1.z + hb1.w;
    uint32_t x0 = sl0, x1 = sl1;
#pragma unroll
    for (int off = 1; off < 64; off <<= 1) {
      uint32_t y0 = __shfl_up(x0, off);
      uint32_t y1 = __shfl_up(x1, off);
      if (lane >= off) { x0 += y0; x1 += y1; }
    }
    uint32_t P0 = x0 - sl0, P1 = x1 - sl1;
    uint32_t harr0[8] = { hb0.w, hb0.z, hb0.y, hb0.x, ha0.w, ha0.z, ha0.y, ha0.x };
    uint32_t harr1[8] = { hb1.w, hb1.z, hb1.y, hb1.x, ha1.w, ha1.z, ha1.y, ha1.x };
    uint32_t cb0 = P0, G0 = 0, cb1 = P1, G1 = 0;
    int fc0 = -1, fc1 = -1;
#pragma unroll
    for (int c = 0; c < 8; c++) {
      uint32_t hc0 = harr0[c], hc1 = harr1[c];
      if (fc0 < 0 && (int)cb0 < 64 && (int)(cb0 + hc0) >= 64) { fc0 = c; G0 = cb0; }
      if (fc1 < 0 && (int)cb1 < 64 && (int)(cb1 + hc1) >= 64) { fc1 = c; G1 = cb1; }
      cb0 += hc0; cb1 += hc1;
    }
    uint64_t fm0 = __ballot(fc0 >= 0), fm1 = __ballot(fc1 >= 0);
    int src0 = __ffsll((unsigned long long)fm0) - 1;
    int src1 = __ffsll((unsigned long long)fm1) - 1;
    int Bstar0 = __shfl((fc0 >= 0) ? (511 - 8 * lane - fc0) : 0, src0);
    int Bstar1 = __shfl((fc1 >= 0) ? (511 - 8 * lane - fc1) : 0, src1);
    int Gs0 = __shfl((int)G0, src0), Gs1 = __shfl((int)G1, src1);
    int needed0 = 64 - Gs0, needed1 = 64 - Gs1;
    wave_fence();                                          // F3

    // interleaved pass 1: bin > Bstar -> selected; bin == Bstar -> candidate
    int pos0 = 0, cT0 = 0, pos1 = 0, cT1 = 0;
#pragma unroll
    for (int i = 0; i < 16; i++) {
      int b0 = (int)fmaxf(0.f, fminf(511.f, fmaf(fv[0][i], 32.f, 256.f)));
      int b1 = (int)fmaxf(0.f, fminf(511.f, fmaf(fv[1][i], 32.f, 256.f)));
      bool hi0 = b0 > Bstar0, cd0 = (b0 == Bstar0);
      bool hi1 = b1 > Bstar1, cd1 = (b1 == Bstar1);
      uint64_t hm0 = __ballot(hi0), em0 = __ballot(cd0);
      uint64_t hm1 = __ballot(hi1), em1 = __ballot(cd1);
      int p0  = pos0 + (int)__popcll(hm0 & lt);
      int cp0 = cT0  + (int)__popcll(em0 & lt);
      int p1  = pos1 + (int)__popcll(hm1 & lt);
      int cp1 = cT1  + (int)__popcll(em1 & lt);
      if (hi0) { selWw[p0] = fv[0][i]; selIw[p0] = (ushort)(i * 64 + lane); }
      if (cd0 && cp0 < 64) { candV0[cp0] = fv[0][i]; candI0[cp0] = (ushort)(i * 64 + lane); }
      if (hi1) { selWw[64 + p1] = fv[1][i]; selIw[64 + p1] = (ushort)(i * 64 + lane); }
      if (cd1 && cp1 < 64) { candV1[cp1] = fv[1][i]; candI1[cp1] = (ushort)(i * 64 + lane); }
      pos0 += (int)__popcll(hm0); cT0 += (int)__popcll(em0);
      pos1 += (int)__popcll(hm1); cT1 += (int)__popcll(em1);
    }
    wave_fence();                                          // F4
    // interleaved exact ranking inside boundary bins (value desc, index asc)
    int C0 = cT0 < 64 ? cT0 : 64;
    int C1 = cT1 < 64 ? cT1 : 64;
    float mv0 = candV0[lane]; int mi0 = candI0[lane]; int rank0 = 0;
    float mv1 = candV1[lane]; int mi1 = candI1[lane]; int rank1 = 0;
    int Cm = C0 > C1 ? C0 : C1;
    for (int i = 0; i < Cm; i++) {       // LDS broadcast reads, 2-way ILP
      if (i < C0) {
        float ov = candV0[i]; int oi = candI0[i];
        rank0 += (ov > mv0 || (ov == mv0 && oi < mi0)) ? 1 : 0;
      }
      if (i < C1) {
        float ov = candV1[i]; int oi = candI1[i];
        rank1 += (ov > mv1 || (ov == mv1 && oi < mi1)) ? 1 : 0;
      }
    }
    bool take0 = (lane < C0) && (rank0 < needed0);
    bool take1 = (lane < C1) && (rank1 < needed1);
    uint64_t tm0 = __ballot(take0), tm1 = __ballot(take1);
    int slot0 = Gs0 + (int)__popcll(tm0 & lt);
    int slot1 = Gs1 + (int)__popcll(tm1 & lt);
    if (take0) { selWw[slot0] = mv0; selIw[slot0] = (ushort)mi0; }
    if (take1) { selWw[64 + slot1] = mv1; selIw[64 + slot1] = (ushort)mi1; }
    wave_fence();                                          // F5
    // interleaved softmax over the 64 selected scores of each query
    float sv0 = selWw[lane], sv1 = selWw[64 + lane];
    float mx0 = sv0, mx1 = sv1;
#pragma unroll
    for (int off = 32; off >= 1; off >>= 1) {
      mx0 = fmaxf(mx0, __shfl_xor(mx0, off));
      mx1 = fmaxf(mx1, __shfl_xor(mx1, off));
    }
    float e0 = __expf(sv0 - mx0), e1 = __expf(sv1 - mx1);
    float sum0 = e0, sum1 = e1;
#pragma unroll
    for (int off = 32; off >= 1; off >>= 1) {
      sum0 += __shfl_xor(sum0, off);
      sum1 += __shfl_xor(sum1, off);
    }
    selWw[lane] = e0 / sum0;
    selWw[64 + lane] = e1 / sum1;
    wave_fence();                                          // F6
  }
  // NO block barrier: PV consumes this wave's own selW/selI only.

  // ---- PV (wave-local): lane -> ql = lane>>5, jh = (lane>>4)&1,
  //      d-block = (lane&15)*4. 16-deep batched gather prefetch.
  {
    int ql = lane >> 5, jh = (lane >> 4) & 1, dblk = (lane & 15) * 4;
    const float* vb = vg + (size_t)bh * SS * HD;
    f32x4 a4 = {};
#pragma unroll
    for (int bch = 0; bch < 2; bch++) {
      float wreg[16]; int ireg[16];
#pragma unroll
      for (int j = 0; j < 16; j++) {
        int jj = jh * 32 + bch * 16 + j;
        wreg[j] = selWw[ql * 64 + jj];
        ireg[j] = selIw[ql * 64 + jj];
      }
#pragma unroll
      for (int j = 0; j < 16; j++) {
        f32x4 v4 = *(const f32x4*)(vb + (size_t)ireg[j] * HD + dblk);
        a4 += wreg[j] * v4;
      }
    }
#pragma unroll
    for (int c = 0; c < 4; c++) a4[c] += __shfl_xor(a4[c], 16);
    if (jh == 0) {
      int qg = q0 + 2 * wv + ql;
      size_t dofs = ((size_t)b_ * SS + qg) * EE + h_ * HD + dblk;
      bf16x4 oh, om;
#pragma unroll
      for (int j = 0; j < 4; j++) {
        bf16_t hh = (bf16_t)a4[j];
        oh[j] = hh;
        om[j] = (bf16_t)(a4[j] - (float)hh);
      }
      *(bf16x4*)(attnH + dofs) = oh;
      *(bf16x4*)(attnM + dofs) = om;
    }
  }
}

// ---------------------------------------------------------------------------
extern "C" void kernel_launch(void* const* d_in, const int* in_sizes, int n_in,
                              void* d_out, int out_size, void* d_ws, size_t ws_size,
                              hipStream_t stream)
{
  const float* x  = (const float*)d_in[0];
  const float* Wq = (const float*)d_in[1];
  const float* bq = (const float*)d_in[2];
  const float* Wk = (const float*)d_in[3];
  const float* bk = (const float*)d_in[4];
  const float* Wv = (const float*)d_in[5];
  const float* bv = (const float*)d_in[6];
  const float* Wo = (const float*)d_in[7];
  const float* bo = (const float*)d_in[8];

  bf16_t* base = (bf16_t*)d_ws;
  bf16_t *xh = base,            *xm = xh + NX_,  *xl = xm + NX_;
  bf16_t *wqh = base + 3*NX_,           *wqm = wqh + NW_, *wql = wqm + NW_;
  bf16_t *wkh = base + 3*NX_ + 3*NW_,   *wkm = wkh + NW_, *wkl = wkm + NW_;
  bf16_t *wvh = base + 3*NX_ + 6*NW_,   *wvm = wvh + NW_;
  bf16_t *woh = base + 3*NX_ + 9*NW_,   *wom = woh + NW_;
  bf16_t *p2 = base + 3*NX_ + 12*NW_;
  bf16_t *qh = p2,          *qm = qh + NX_, *ql = qm + NX_;
  bf16_t *kh = ql + NX_,    *km = kh + NX_, *kl = km + NX_;
  float  *vws = (float*)(kl + NX_);
  bf16_t *ath = (bf16_t*)(vws + NX_), *atm = ath + NX_;

  dim3 blk(256);
  presplit_all<<<dim3(6144), blk, 0, stream>>>(x, Wq, Wk, Wv, Wo, base);

  // fused Q+K: 128x64 tile, grid (16, 16, 2) = 512 blocks (2/CU)
  gemm_qk<<<dim3(EE / 64, (NB * SS) / 128, 2), blk, 0, stream>>>(
      xh, xm, xl, wqh, wqm, wql, wkh, wkm, wkl, bq, bk,
      qh, qm, ql, kh, km, kl);

  // V: 64x64 tile, grid (16, 32) = 512 blocks (2/CU)
  gemm_nl2<1><<<dim3(EE / 64, (NB * SS) / 64), blk, 0, stream>>>(
      xh, xm, wvh, wvm, bv, vws);

  attn_topk<<<dim3(NBH * (SS / 16)), dim3(512), 0, stream>>>(
      qh, qm, ql, kh, km, kl, vws, ath, atm);

  // O: 64x64 tile, grid (16, 32) = 512 blocks (2/CU)
  gemm_nl2<2><<<dim3(EE / 64, (NB * SS) / 64), blk, 0, stream>>>(
      ath, atm, woh, wom, bo, (float*)d_out);
}